// Round 6
// baseline (236.603 us; speedup 1.0000x reference)
//
#include <hip/hip_runtime.h>
#include <hip/hip_bf16.h>

// TransformerLayer on MI355X (gfx950). Round 6:
//  - attn_fused: rowsum + P/PV merged in one kernel, QBLK=32 (1024 blocks,
//    2 scheduling rounds -> backfill fixes causal load imbalance).
//    Pass A: TK=64 K-dbuf, 16-col wave strips (16 MFMA : 8 ds_read_b128).
//    Pass B: TK=32 K/V-dbuf; P store counted in vmcnt (9) so loop never
//    drains the previous P write. lgkmcnt(0) before every raw barrier
//    that follows LDS writes (R4 race lesson).
//  - GEMM stack unchanged from round 5.

typedef __bf16 bf16_t;
typedef __bf16 bf16x8 __attribute__((ext_vector_type(8)));
typedef __bf16 bf16x4 __attribute__((ext_vector_type(4)));
typedef float  f32x4  __attribute__((ext_vector_type(4)));

#define DEV __device__ __forceinline__

DEV f32x4 mfma16(bf16x8 a, bf16x8 b, f32x4 c) {
  return __builtin_amdgcn_mfma_f32_16x16x32_bf16(a, b, c, 0, 0, 0);
}

DEV void gload16(const void* g, void* l) {
  __builtin_amdgcn_global_load_lds(
      (const __attribute__((address_space(1))) unsigned int*)g,
      (__attribute__((address_space(3))) unsigned int*)l, 16, 0, 0);
}

// ---------------- fused LN1 + weight cvt (grid 1024 + 2560) ----------------
__global__ __launch_bounds__(256) void k1_lncvt(
    const float* __restrict__ x, const float* __restrict__ g, const float* __restrict__ bta,
    float* __restrict__ of, bf16_t* __restrict__ ob,
    const float* __restrict__ s0, const float* __restrict__ s1,
    const float* __restrict__ s2, const float* __restrict__ s3,
    const float* __restrict__ s4, const float* __restrict__ s5,
    bf16_t* __restrict__ d0, bf16_t* __restrict__ d1, bf16_t* __restrict__ d2,
    bf16_t* __restrict__ d3, bf16_t* __restrict__ d4, bf16_t* __restrict__ d5) {
  int bid = blockIdx.x;
  if (bid < 1024) {
    int row = bid * 4 + (threadIdx.x >> 6);
    int l = threadIdx.x & 63;
    const float4 v = *(const float4*)(x + (size_t)row * 256 + l * 4);
    float s  = v.x + v.y + v.z + v.w;
    float s2 = v.x*v.x + v.y*v.y + v.z*v.z + v.w*v.w;
#pragma unroll
    for (int o = 1; o < 64; o <<= 1) { s += __shfl_xor(s, o, 64); s2 += __shfl_xor(s2, o, 64); }
    float m   = s * (1.f/256.f);
    float var = s2 * (1.f/256.f) - m * m;
    float rs  = rsqrtf(var + 1e-9f);
    const float4 gv = *(const float4*)(g   + l * 4);
    const float4 bv = *(const float4*)(bta + l * 4);
    float4 y;
    y.x = (v.x - m) * rs * gv.x + bv.x;
    y.y = (v.y - m) * rs * gv.y + bv.y;
    y.z = (v.z - m) * rs * gv.z + bv.z;
    y.w = (v.w - m) * rs * gv.w + bv.w;
    *(float4*)(of + (size_t)row * 256 + l * 4) = y;
    bf16x4 yb = { (bf16_t)y.x, (bf16_t)y.y, (bf16_t)y.z, (bf16_t)y.w };
    *(bf16x4*)(ob + (size_t)row * 256 + l * 4) = yb;
  } else {
    int i = (bid - 1024) * 256 + threadIdx.x;
    const float* s; bf16_t* d; int off;
    if      (i < 131072) { s = s0; d = d0; off = i; }
    else if (i < 262144) { s = s1; d = d1; off = i - 131072; }
    else if (i < 393216) { s = s2; d = d2; off = i - 262144; }
    else if (i < 524288) { s = s3; d = d3; off = i - 393216; }
    else if (i < 589824) { s = s4; d = d4; off = i - 524288; }
    else                 { s = s5; d = d5; off = i - 589824; }
    float4 v = ((const float4*)s)[off];
    bf16x4 o = { (bf16_t)v.x, (bf16_t)v.y, (bf16_t)v.z, (bf16_t)v.w };
    ((bf16x4*)d)[off] = o;
  }
}

// ---------------- 2-phase double-buffered 128x128 GEMM core ----------------
DEV void gemm_core(const bf16_t* __restrict__ A, const bf16_t* __restrict__ W,
                   int lda, int row0, int col0, int k0, int kiters,
                   char* Asb, char* Bsb, f32x4 (&acc)[4][4]) {
  int tid = threadIdx.x, w = tid >> 6, l = tid & 63, l15 = l & 15, lhi = l >> 4;
  int wr = (w >> 1) * 64, wc = (w & 1) * 64;

#define STAGE(buf, kk) do {                                                   \
    char* Ad = Asb + (buf) * 8192 + w * 1024;                                 \
    char* Bd = Bsb + (buf) * 8192 + w * 1024;                                 \
    _Pragma("unroll")                                                         \
    for (int j = 0; j < 2; ++j) {                                             \
      int idx = (j * 256 + tid) * 8; int r = idx >> 5, c = idx & 31;          \
      gload16(A + (size_t)(row0 + r) * lda + (kk) + c, Ad + j * 4096);        \
      gload16(W + (size_t)(col0 + r) * lda + (kk) + c, Bd + j * 4096);        \
    } } while (0)

  STAGE(0, k0);
  for (int t = 0; t < kiters; ++t) {
    int cur = t & 1;
    if (t + 1 < kiters) {
      STAGE(cur ^ 1, k0 + (t + 1) * 32);
      asm volatile("s_waitcnt vmcnt(4)" ::: "memory");
    } else {
      asm volatile("s_waitcnt vmcnt(0)" ::: "memory");
    }
    __builtin_amdgcn_s_barrier();
    asm volatile("" ::: "memory");
    const bf16_t* As = (const bf16_t*)(Asb + cur * 8192);
    const bf16_t* Bs = (const bf16_t*)(Bsb + cur * 8192);
    bf16x8 af[4], bfr[4];
#pragma unroll
    for (int m = 0; m < 4; ++m)
      af[m] = *(const bf16x8*)(As + (wr + 16 * m + l15) * 32 + lhi * 8);
#pragma unroll
    for (int n = 0; n < 4; ++n)
      bfr[n] = *(const bf16x8*)(Bs + (wc + 16 * n + l15) * 32 + lhi * 8);
#pragma unroll
    for (int m = 0; m < 4; ++m)
#pragma unroll
      for (int n = 0; n < 4; ++n)
        acc[m][n] = mfma16(af[m], bfr[n], acc[m][n]);
    asm volatile("s_waitcnt lgkmcnt(0)" ::: "memory");
    __builtin_amdgcn_s_barrier();
  }
#undef STAGE
}

// ---------------- fused QKV: grid (48, 32); V writes V^T via LDS transpose ----------------
__global__ __launch_bounds__(256, 4) void gemm_qkv(
    const bf16_t* __restrict__ A,
    const bf16_t* __restrict__ W0, const bf16_t* __restrict__ W1, const bf16_t* __restrict__ W2,
    const float* __restrict__ b0, const float* __restrict__ b1, const float* __restrict__ b2,
    bf16_t* __restrict__ qo, bf16_t* __restrict__ ko, bf16_t* __restrict__ vto) {
  __shared__ char smem[34816];   // staging 32KB | V-transpose 128x136 bf16
  char* Asb = smem;
  char* Bsb = smem + 16384;
  int bx = blockIdx.x;
  int wsel = bx >> 4, cb = bx & 15;
  const bf16_t* W    = wsel == 0 ? W0 : (wsel == 1 ? W1 : W2);
  const float*  bias = wsel == 0 ? b0 : (wsel == 1 ? b1 : b2);
  int row0 = blockIdx.y * 128, col0 = cb * 128;
  f32x4 acc[4][4] = {};
  gemm_core(A, W, 256, row0, col0, 0, 8, Asb, Bsb, acc);

  int tid = threadIdx.x, w = tid >> 6, l = tid & 63, l15 = l & 15, lhi = l >> 4;
  int wr = (w >> 1) * 64, wc = (w & 1) * 64;

  if (wsel < 2) {
    bf16_t* out = wsel == 0 ? qo : ko;
#pragma unroll
    for (int m = 0; m < 4; ++m)
#pragma unroll
      for (int n = 0; n < 4; ++n)
#pragma unroll
        for (int j = 0; j < 4; ++j) {
          int row = row0 + wr + 16 * m + lhi * 4 + j;
          int col = col0 + wc + 16 * n + l15;
          float v = acc[m][n][j] + bias[col];
          out[((size_t)((row >> 11) * 8 + (col >> 8)) * 2048 + (row & 2047)) * 256 + (col & 255)] = (bf16_t)v;
        }
  } else {
    // V: transpose in LDS, write V^T (B,H,Dh,S)
    __syncthreads();   // full drain before overwriting staging LDS
    bf16_t* T = (bf16_t*)smem;   // [128 d][136 stride] bf16
#pragma unroll
    for (int m = 0; m < 4; ++m)
#pragma unroll
      for (int n = 0; n < 4; ++n) {
        int d = wc + 16 * n + l15;
        int s = wr + 16 * m + lhi * 4;
        bf16x4 v4;
#pragma unroll
        for (int j = 0; j < 4; ++j) v4[j] = (bf16_t)(acc[m][n][j] + bias[col0 + d]);
        *(bf16x4*)(T + d * 136 + s) = v4;
      }
    __syncthreads();
    int bh = ((row0 >> 11) << 3) + (col0 >> 8);
    int d0 = col0 & 255, s0g = row0 & 2047;
#pragma unroll
    for (int p = 0; p < 8; ++p) {
      int idx = p * 256 + tid;
      int d = idx >> 4, c = (idx & 15) * 8;
      bf16x8 v8 = *(const bf16x8*)(T + d * 136 + c);
      *(bf16x8*)(vto + ((size_t)bh * 256 + d0 + d) * 2048 + s0g + c) = v8;
    }
  }
}

// ---------------- split-K partial GEMM: N=256, grid (2, 32, 4) ----------------
__global__ __launch_bounds__(256, 4) void gemm_part(
    const bf16_t* __restrict__ A, const bf16_t* __restrict__ W,
    int lda, int ksub, float* __restrict__ parts) {
  __shared__ char Asb[2 * 8192];
  __shared__ char Bsb[2 * 8192];
  int z = blockIdx.z;
  int row0 = blockIdx.y * 128, col0 = blockIdx.x * 128;
  f32x4 acc[4][4] = {};
  gemm_core(A, W, lda, row0, col0, z * ksub, ksub >> 5, Asb, Bsb, acc);

  int tid = threadIdx.x, w = tid >> 6, l = tid & 63, l15 = l & 15, lhi = l >> 4;
  int wr = (w >> 1) * 64, wc = (w & 1) * 64;
  float* p = parts + (size_t)z * 1048576;
#pragma unroll
  for (int m = 0; m < 4; ++m)
#pragma unroll
    for (int n = 0; n < 4; ++n)
#pragma unroll
      for (int j = 0; j < 4; ++j) {
        int row = row0 + wr + 16 * m + lhi * 4 + j;
        int col = col0 + wc + 16 * n + l15;
        p[(size_t)row * 256 + col] = acc[m][n][j];
      }
}

// ---------------- reduce 4 partials + bias + residual (final out) ----------------
__global__ __launch_bounds__(256) void reduce4(
    const float* __restrict__ parts, const float* __restrict__ bias,
    const float* __restrict__ res, float* __restrict__ out) {
  int i = blockIdx.x * 256 + threadIdx.x;
  f32x4 s = *(const f32x4*)(parts + (size_t)i * 4);
  s += *(const f32x4*)(parts + 1048576 + (size_t)i * 4);
  s += *(const f32x4*)(parts + 2097152 + (size_t)i * 4);
  s += *(const f32x4*)(parts + 3145728 + (size_t)i * 4);
  s += *(const f32x4*)(res + (size_t)i * 4);
  s += *(const f32x4*)(bias + (i & 63) * 4);
  *(f32x4*)(out + (size_t)i * 4) = s;
}

// ---------------- fused dense-reduce + residual + LN2 ----------------
__global__ __launch_bounds__(256) void reduce_ln(
    const float* __restrict__ parts, const float* __restrict__ bias,
    const float* __restrict__ res, const float* __restrict__ g,
    const float* __restrict__ bta, float* __restrict__ x1o, bf16_t* __restrict__ mo) {
  int row = blockIdx.x * 4 + (threadIdx.x >> 6);
  int l = threadIdx.x & 63;
  size_t base = (size_t)row * 256 + l * 4;
  f32x4 s = *(const f32x4*)(parts + base);
  s += *(const f32x4*)(parts + 1048576 + base);
  s += *(const f32x4*)(parts + 2097152 + base);
  s += *(const f32x4*)(parts + 3145728 + base);
  s += *(const f32x4*)(res + base);
  s += *(const f32x4*)(bias + l * 4);
  *(f32x4*)(x1o + base) = s;
  float sm = s[0] + s[1] + s[2] + s[3];
  float s2 = s[0]*s[0] + s[1]*s[1] + s[2]*s[2] + s[3]*s[3];
#pragma unroll
  for (int o = 1; o < 64; o <<= 1) { sm += __shfl_xor(sm, o, 64); s2 += __shfl_xor(s2, o, 64); }
  float m   = sm * (1.f/256.f);
  float var = s2 * (1.f/256.f) - m * m;
  float rs  = rsqrtf(var + 1e-9f);
  const float4 gv = *(const float4*)(g   + l * 4);
  const float4 bv = *(const float4*)(bta + l * 4);
  bf16x4 yb;
  yb[0] = (bf16_t)((s[0] - m) * rs * gv.x + bv.x);
  yb[1] = (bf16_t)((s[1] - m) * rs * gv.y + bv.y);
  yb[2] = (bf16_t)((s[2] - m) * rs * gv.z + bv.z);
  yb[3] = (bf16_t)((s[3] - m) * rs * gv.w + bv.w);
  *(bf16x4*)(mo + base) = yb;
}

// ---------------- FC1 with gelu ----------------
__global__ __launch_bounds__(256, 4) void gemm_fc1(
    const bf16_t* __restrict__ A, const bf16_t* __restrict__ W,
    const float* __restrict__ bias, bf16_t* __restrict__ out) {
  __shared__ char Asb[2 * 8192];
  __shared__ char Bsb[2 * 8192];
  int row0 = blockIdx.y * 128, col0 = blockIdx.x * 128;
  f32x4 acc[4][4] = {};
  gemm_core(A, W, 256, row0, col0, 0, 8, Asb, Bsb, acc);

  int tid = threadIdx.x, w = tid >> 6, l = tid & 63, l15 = l & 15, lhi = l >> 4;
  int wr = (w >> 1) * 64, wc = (w & 1) * 64;
#pragma unroll
  for (int m = 0; m < 4; ++m)
#pragma unroll
    for (int n = 0; n < 4; ++n)
#pragma unroll
      for (int j = 0; j < 4; ++j) {
        int row = row0 + wr + 16 * m + lhi * 4 + j;
        int col = col0 + wc + 16 * n + l15;
        float t = acc[m][n][j] + bias[col];
        float ge = 0.5f * t * (1.f + tanhf(0.7978845608f * t * (1.f + 0.044715f * t * t)));
        out[(size_t)row * 1024 + col] = (bf16_t)ge;
      }
}

// ---------------- fused attention: rowsum (pass A) + P/PV (pass B) ----------------
// grid 1024: bh = bx&15, qt = 63 - (bx>>4) (32-row q tiles, longest first)
__global__ __launch_bounds__(256, 2) void attn_fused(
    const bf16_t* __restrict__ qg, const bf16_t* __restrict__ kg,
    const bf16_t* __restrict__ vt, float* __restrict__ pout,
    bf16_t* __restrict__ ctxo) {
  // union layout:
  //  pass A: KA = smem[0..65536) (2 x 32KB TK=64 dbuf); sl @65536 (512B)
  //  pass B: KB = smem[0..32768) (2x16KB), VB = smem[32768..65536) (2x16KB),
  //          Psh @65536 (2KB)
  //  invsh @67584 (128B) — live across both passes
  __shared__ __align__(16) char smem[67712];
  int bx = blockIdx.x;
  int bh = bx & 15, qt = 63 - (bx >> 4);
  int tid = threadIdx.x, w = tid >> 6, l = tid & 63;
  int l15 = l & 15, lhi = l >> 4;
  const bf16_t* Q   = qg + (size_t)bh * 2048 * 256;
  const bf16_t* Kg2 = kg + (size_t)bh * 2048 * 256;
  const bf16_t* Vt  = vt + (size_t)bh * 256 * 2048;
  int qbase = qt * 32;
  float* sl    = (float*)(smem + 65536);
  float* invsh = (float*)(smem + 67584);

  // Q fragments: rows qbase + m*16 + l15 (all waves same 32 rows)
  bf16x8 qf[2][8];
#pragma unroll
  for (int m = 0; m < 2; ++m)
#pragma unroll
    for (int ks = 0; ks < 8; ++ks)
      qf[m][ks] = *(const bf16x8*)(Q + (size_t)(qbase + m * 16 + l15) * 256 + ks * 32 + lhi * 8);

  // ---- pass A: masked exp rowsums, TK=64, wave = 16-col strip ----
  char* KA = smem;
  int nktA = (qt >> 1) + 1;
#define ASTAGE(t_) do {                                                        \
    char* dst = KA + ((t_) & 1) * 32768 + w * 1024;                            \
    _Pragma("unroll")                                                          \
    for (int j = 0; j < 8; ++j) {                                              \
      int idx = (j * 256 + tid) * 16; int r = idx >> 9;                        \
      int co = (idx & 511) ^ ((r & 7) << 4);                                   \
      gload16(Kg2 + (size_t)((t_) * 64 + r) * 256 + (co >> 1), dst + j * 4096);\
    } } while (0)
  ASTAGE(0);
  if (nktA > 1) ASTAGE(1);

  float sums[2][4] = {};
  for (int t = 0; t < nktA; ++t) {
    if (t + 1 < nktA) asm volatile("s_waitcnt vmcnt(8)" ::: "memory");
    else              asm volatile("s_waitcnt vmcnt(0)" ::: "memory");
    __builtin_amdgcn_s_barrier();
    const char* Kb = KA + (t & 1) * 32768;
    int row = w * 16 + l15;
    f32x4 acc[2] = {};
    __builtin_amdgcn_s_setprio(1);
#pragma unroll
    for (int ks = 0; ks < 8; ++ks) {
      bf16x8 kb = *(const bf16x8*)(Kb + row * 512 + ((ks * 64 + lhi * 16) ^ ((row & 7) << 4)));
      acc[0] = mfma16(qf[0][ks], kb, acc[0]);
      acc[1] = mfma16(qf[1][ks], kb, acc[1]);
    }
    __builtin_amdgcn_s_setprio(0);
#pragma unroll
    for (int m = 0; m < 2; ++m)
#pragma unroll
      for (int j = 0; j < 4; ++j) {
        int qr = qbase + m * 16 + lhi * 4 + j;
        int kc = t * 64 + row;
        sums[m][j] += (kc <= qr) ? __expf(acc[m][j] * 0.0625f) : 0.f;
      }
    asm volatile("s_waitcnt lgkmcnt(0)" ::: "memory");
    __builtin_amdgcn_s_barrier();
    if (t + 2 < nktA) ASTAGE(t + 2);
  }
#undef ASTAGE

#pragma unroll
  for (int m = 0; m < 2; ++m)
#pragma unroll
    for (int j = 0; j < 4; ++j)
#pragma unroll
      for (int o = 1; o < 16; o <<= 1)
        sums[m][j] += __shfl_xor(sums[m][j], o, 64);
  if (l15 == 0)
#pragma unroll
    for (int m = 0; m < 2; ++m)
#pragma unroll
      for (int j = 0; j < 4; ++j)
        sl[w * 32 + m * 16 + lhi * 4 + j] = sums[m][j];
  __syncthreads();
  if (tid < 32)
    invsh[tid] = 1.f / (sl[tid] + sl[32 + tid] + sl[64 + tid] + sl[96 + tid]);
  __syncthreads();

  // ---- pass B: P write + PV, TK=32, waves (wm,wn) for QK, d-split for PV ----
  char* KB  = smem;
  char* VB  = smem + 32768;
  char* Psh = smem + 65536;
  int wm = w >> 1, wn = w & 1;
  float inv4[4];
#pragma unroll
  for (int j = 0; j < 4; ++j) inv4[j] = invsh[wm * 16 + lhi * 4 + j];

  int nktB = qt + 1;
#define BSTAGE(t_) do {                                                         \
    char* kd = KB + ((t_) & 1) * 16384 + w * 1024;                              \
    char* vd = VB + ((t_) & 1) * 16384 + w * 1024;                              \
    _Pragma("unroll")                                                           \
    for (int j = 0; j < 4; ++j) {                                               \
      int idx = (j * 256 + tid) * 16;                                           \
      { int r = idx >> 9; int co = (idx & 511) ^ ((r & 7) << 4);                \
        gload16(Kg2 + (size_t)((t_) * 32 + r) * 256 + (co >> 1), kd + j * 4096); } \
      { int r = idx >> 6; int co = (idx & 63) ^ (((r >> 2) & 3) << 4);          \
        gload16(Vt + (size_t)r * 2048 + (t_) * 32 + (co >> 1), vd + j * 4096); } \
    } } while (0)
  BSTAGE(0);
  if (nktB > 1) BSTAGE(1);

  f32x4 ctx[2][4] = {};
  for (int t = 0; t < nktB; ++t) {
    // vmcnt: steady state has [tile t (8), P-store (1), tile t+1 (8)] pending
    if (t + 1 >= nktB)      asm volatile("s_waitcnt vmcnt(0)" ::: "memory");
    else if (t == 0)        asm volatile("s_waitcnt vmcnt(8)" ::: "memory");
    else                    asm volatile("s_waitcnt vmcnt(9)" ::: "memory");
    __builtin_amdgcn_s_barrier();
    const char* Kb = KB + (t & 1) * 16384;
    const char* Vb = VB + (t & 1) * 16384;

    // QK: wave (wm,wn) -> rows [wm*16,+16) x cols [wn*16,+16)
    f32x4 acc = {};
    int krow = wn * 16 + l15;
    __builtin_amdgcn_s_setprio(1);
#pragma unroll
    for (int ks = 0; ks < 8; ++ks) {
      bf16x8 kb = *(const bf16x8*)(Kb + krow * 512 + ((ks * 64 + lhi * 16) ^ ((krow & 7) << 4)));
      acc = mfma16(qf[wm][ks], kb, acc);
    }
    __builtin_amdgcn_s_setprio(0);
#pragma unroll
    for (int j = 0; j < 4; ++j) {
      int rr = wm * 16 + lhi * 4 + j;
      int qr = qbase + rr;
      int kc = t * 32 + krow;
      float e = (kc <= qr) ? __expf(acc[j] * 0.0625f) * inv4[j] : 0.f;
      int addr = rr * 64 + krow * 2;
      *(bf16_t*)(Psh + (addr ^ (((rr >> 2) & 3) << 4))) = (bf16_t)e;
    }
    asm volatile("s_waitcnt lgkmcnt(0)" ::: "memory");   // P writes visible
    __builtin_amdgcn_s_barrier();

    // PV: wave w -> d-cols [w*64,+64), rows 32
    bf16x8 pa[2], vb[4];
#pragma unroll
    for (int m = 0; m < 2; ++m) {
      int pr = m * 16 + l15;
      pa[m] = *(const bf16x8*)(Psh + ((pr * 64 + lhi * 16) ^ (((pr >> 2) & 3) << 4)));
    }
#pragma unroll
    for (int n = 0; n < 4; ++n) {
      int vr = w * 64 + n * 16 + l15;
      vb[n] = *(const bf16x8*)(Vb + ((vr * 64 + lhi * 16) ^ (((vr >> 2) & 3) << 4)));
    }
    __builtin_amdgcn_s_setprio(1);
#pragma unroll
    for (int m = 0; m < 2; ++m)
#pragma unroll
      for (int n = 0; n < 4; ++n)
        ctx[m][n] = mfma16(pa[m], vb[n], ctx[m][n]);
    __builtin_amdgcn_s_setprio(0);

    // dump P -> pout (f32, coalesced); store issued last, never drained in-loop
    {
      int prow = tid >> 3, chunk = tid & 7;
      const char* src = Psh + prow * 64 + ((chunk * 8) ^ (((prow >> 2) & 3) << 4));
      bf16x4 p4 = *(const bf16x4*)src;
      f32x4 o = { (float)p4[0], (float)p4[1], (float)p4[2], (float)p4[3] };
      *(f32x4*)(pout + ((size_t)bh * 2048 + qbase + prow) * 2048 + t * 32 + chunk * 4) = o;
    }
    asm volatile("s_waitcnt lgkmcnt(0)" ::: "memory");   // all Psh/KB/VB reads done
    __builtin_amdgcn_s_barrier();
    if (t + 2 < nktB) BSTAGE(t + 2);
  }
#undef BSTAGE

  // ctx write: (b, s, h*256 + d) bf16
  int b = bh >> 3, h = bh & 7;
#pragma unroll
  for (int m = 0; m < 2; ++m)
#pragma unroll
    for (int n = 0; n < 4; ++n)
#pragma unroll
      for (int j = 0; j < 4; ++j) {
        int qr = qbase + m * 16 + lhi * 4 + j;
        ctxo[((size_t)b * 2048 + qr) * 2048 + h * 256 + w * 64 + n * 16 + l15] = (bf16_t)ctx[m][n][j];
      }

  // zero-fill masked upper region
  int zs = qbase + 32;
  for (int r = 0; r < 32; ++r) {
    size_t base2 = ((size_t)bh * 2048 + qbase + r) * 2048;
    for (int c = zs + tid * 4; c < 2048; c += 1024)
      *(float4*)(pout + base2 + c) = make_float4(0.f, 0.f, 0.f, 0.f);
  }
}

// ---------------- host launch ----------------
extern "C" void kernel_launch(void* const* d_in, const int* in_sizes, int n_in,
                              void* d_out, int out_size, void* d_ws, size_t ws_size,
                              hipStream_t stream) {
  const float* x     = (const float*)d_in[0];
  const float* ln1g  = (const float*)d_in[2];
  const float* ln1b  = (const float*)d_in[3];
  const float* wq_w  = (const float*)d_in[4];
  const float* wq_b  = (const float*)d_in[5];
  const float* wk_w  = (const float*)d_in[6];
  const float* wk_b  = (const float*)d_in[7];
  const float* wv_w  = (const float*)d_in[8];
  const float* wv_b  = (const float*)d_in[9];
  const float* dw    = (const float*)d_in[10];
  const float* db    = (const float*)d_in[11];
  const float* ln2g  = (const float*)d_in[12];
  const float* ln2b  = (const float*)d_in[13];
  const float* f1w   = (const float*)d_in[14];
  const float* f1b   = (const float*)d_in[15];
  const float* f2w   = (const float*)d_in[16];
  const float* f2b   = (const float*)d_in[17];

  char* ws = (char*)d_ws;
  const size_t MB = 1u << 20;
  float*  xn_f = (float*) (ws + 0 * MB);
  bf16_t* xn_b = (bf16_t*)(ws + 4 * MB);
  bf16_t* q_b  = (bf16_t*)(ws + 6 * MB);
  bf16_t* k_b  = (bf16_t*)(ws + 22 * MB);
  bf16_t* ctx_b= (bf16_t*)(ws + 38 * MB);
  bf16_t* vt_b = (bf16_t*)(ws + 54 * MB);
  float*  x1_f = (float*) (ws + 70 * MB);
  bf16_t* m_b  = (bf16_t*)(ws + 74 * MB);
  bf16_t* h_b  = (bf16_t*)(ws + 76 * MB);
  bf16_t* wq_bf = (bf16_t*)(ws + 84 * MB);
  bf16_t* wk_bf = wq_bf + 524288;
  bf16_t* wv_bf = wk_bf + 524288;
  bf16_t* dw_bf = wv_bf + 524288;
  bf16_t* f1_bf = dw_bf + 524288;
  bf16_t* f2_bf = f1_bf + 262144;
  float* parts_d = (float*)q_b;
  float* parts_f = (float*)k_b;

  float* out0 = (float*)d_out;
  float* pout = out0 + 1048576;

  k1_lncvt<<<3584, 256, 0, stream>>>(x, ln1g, ln1b, xn_f, xn_b,
                                     wq_w, wk_w, wv_w, dw, f1w, f2w,
                                     wq_bf, wk_bf, wv_bf, dw_bf, f1_bf, f2_bf);

  gemm_qkv<<<dim3(48, 32), 256, 0, stream>>>(xn_b, wq_bf, wk_bf, wv_bf,
                                             wq_b, wk_b, wv_b, q_b, k_b, vt_b);

  attn_fused<<<1024, 256, 0, stream>>>(q_b, k_b, vt_b, pout, ctx_b);

  gemm_part<<<dim3(2, 32, 4), 256, 0, stream>>>(ctx_b, dw_bf, 2048, 512, parts_d);
  reduce_ln<<<1024, 256, 0, stream>>>(parts_d, db, xn_f, ln2g, ln2b, x1_f, m_b);

  gemm_fc1<<<dim3(8, 32), 256, 0, stream>>>(m_b, f1_bf, f1b, h_b);

  gemm_part<<<dim3(2, 32, 4), 256, 0, stream>>>(h_b, f2_bf, 1024, 256, parts_f);
  reduce4<<<1024, 256, 0, stream>>>(parts_f, f2b, x1_f, out0);
}